// Round 6
// baseline (203.566 us; speedup 1.0000x reference)
//
#include <hip/hip_runtime.h>
#include <hip/hip_bf16.h>
#include <stdint.h>

typedef __attribute__((ext_vector_type(8))) short short8;
typedef __attribute__((ext_vector_type(4))) float f32x4;

#define N_SLOTS 65536
#define D_FEAT  64
#define BATCH   2048
#define BM      64               // batch rows per block
#define NC      32               // k-chunks (by)
#define KCHUNK  (N_SLOTS / NC)   // 2048
#define KSTEP   32               // k per MFMA step
#define NITER   (KCHUNK / KSTEP) // 64

// float -> bf16 bits, round-to-nearest-even
__device__ __forceinline__ unsigned short f2bf(float f) {
    unsigned int u = __builtin_bit_cast(unsigned int, f);
    u += 0x7fffu + ((u >> 16) & 1u);
    return (unsigned short)(u >> 16);
}

// Kernel 0: M [N_SLOTS][64] f32 -> MT [64][N_SLOTS] bf16 (runs once, ~4 us)
__global__ __launch_bounds__(256) void convert_mt(const float* __restrict__ M,
                                                  unsigned short* __restrict__ MT) {
    __shared__ unsigned short s[64][72];
    const int t  = threadIdx.x;
    const int k0 = blockIdx.x * 64;
    #pragma unroll
    for (int j = 0; j < 4; ++j) {
        const int r = j * 16 + (t >> 4);
        const int c = (t & 15) * 4;
        const float4 v = *reinterpret_cast<const float4*>(M + (size_t)(k0 + r) * D_FEAT + c);
        s[r][c + 0] = f2bf(v.x); s[r][c + 1] = f2bf(v.y);
        s[r][c + 2] = f2bf(v.z); s[r][c + 3] = f2bf(v.w);
    }
    __syncthreads();
    #pragma unroll
    for (int j = 0; j < 2; ++j) {
        const int d  = j * 32 + (t >> 3);
        const int kk = (t & 7) * 8;
        short8 v;
        #pragma unroll
        for (int e = 0; e < 8; ++e) v[e] = (short)s[kk + e][d];
        *reinterpret_cast<short8*>(MT + (size_t)d * N_SLOTS + k0 + kk) = v;
    }
}

// Main: ZERO LDS, ZERO barriers. Each lane loads its own A fragment (32B
// contiguous) from W, exp+pack in registers, B fragments straight from MT
// (L2-resident via by-per-XCD swizzle). A and B use the same (g,e)->k map,
// so any HW k-permutation cancels (verified R1-R5). Waves fully independent.
__global__ __launch_bounds__(256) void reading_main(
    const unsigned short* __restrict__ MT,  // [64][N_SLOTS] bf16
    const float* __restrict__ W,            // [BATCH][N_SLOTS] f32
    float* __restrict__ out_p,              // [NC][BATCH][64] partials
    float* __restrict__ lrow)               // [BATCH] denominator accum (pre-zeroed)
{
    const int t  = threadIdx.x;
    const int ln = t & 63;
    const int wv = t >> 6;      // wave 0..3 -> batch rows 16*wv..16*wv+15
    const int r  = ln & 15;     // A row within 16 / B d-row low bits / C col
    const int g  = ln >> 4;     // k lane-group 0..3

    // bijective XCD swizzle: XCD (bid&7) hosts by in {4c..4c+3} -> MT slice 1MB, L2-hot
    const int bid = blockIdx.x;
    const int wg  = ((bid & 7) << 7) | (bid >> 3);
    const int by  = wg >> 5;    // 0..31
    const int bx  = wg & 31;    // 0..31
    const int bm0 = bx * BM;
    const size_t kc0 = (size_t)by * KCHUNK;

    // this lane's row-streams (element offsets; lane's k window starts at g*8)
    const float*          wrow = W  + (size_t)(bm0 + 16 * wv + r) * N_SLOTS + kc0 + g * 8;
    const unsigned short* mrow = MT + (size_t)r * N_SLOTS + kc0 + g * 8;   // + td*16*N_SLOTS

    // rotated k-start: spreads the grid's instantaneous address footprint
    const int rot = (bx * 4 + wv) & (NITER - 1);

    float lsum = 0.f;
    f32x4 acc[4];
    #pragma unroll
    for (int td = 0; td < 4; ++td) acc[td] = f32x4{0.f, 0.f, 0.f, 0.f};

    #pragma unroll 2
    for (int i = 0; i < NITER; ++i) {
        int ki = i + rot;
        if (ki >= NITER) ki -= NITER;
        const size_t co = (size_t)ki * KSTEP;

        const float4 w0 = *reinterpret_cast<const float4*>(wrow + co);
        const float4 w1 = *reinterpret_cast<const float4*>(wrow + co + 4);

        const float e0 = __expf(w0.x), e1 = __expf(w0.y);
        const float e2 = __expf(w0.z), e3 = __expf(w0.w);
        const float e4 = __expf(w1.x), e5 = __expf(w1.y);
        const float e6 = __expf(w1.z), e7 = __expf(w1.w);
        lsum += ((e0 + e1) + (e2 + e3)) + ((e4 + e5) + (e6 + e7));

        short8 a;
        a[0] = (short)f2bf(e0); a[1] = (short)f2bf(e1);
        a[2] = (short)f2bf(e2); a[3] = (short)f2bf(e3);
        a[4] = (short)f2bf(e4); a[5] = (short)f2bf(e5);
        a[6] = (short)f2bf(e6); a[7] = (short)f2bf(e7);

        #pragma unroll
        for (int td = 0; td < 4; ++td) {
            const short8 b = *reinterpret_cast<const short8*>(
                mrow + (size_t)td * 16 * N_SLOTS + co);
            acc[td] = __builtin_amdgcn_mfma_f32_16x16x32_bf16(a, b, acc[td], 0, 0, 0);
        }
    }

    // numerator tile -> partials (C/D map col=r, row=g*4+q, verified R1)
    {
        float* op = out_p + (size_t)by * (BATCH * D_FEAT) + (size_t)bm0 * D_FEAT;
        #pragma unroll
        for (int td = 0; td < 4; ++td) {
            #pragma unroll
            for (int q = 0; q < 4; ++q) {
                op[(16 * wv + g * 4 + q) * D_FEAT + 16 * td + r] = acc[td][q];
            }
        }
    }

    // denominator: sum over the 4 g-lanes holding row r, one atomic per row
    float s = lsum;
    s += __shfl_xor(s, 16, 64);
    s += __shfl_xor(s, 32, 64);
    if (ln < 16) atomicAdd(&lrow[bm0 + 16 * wv + ln], s);
}

__global__ __launch_bounds__(256) void reading_finalize(
    const float* __restrict__ out_p, const float* __restrict__ lrow,
    float* __restrict__ out)
{
    const int i = blockIdx.x * 256 + threadIdx.x;   // BATCH*D_FEAT total
    float s = 0.f;
    #pragma unroll
    for (int c = 0; c < NC; ++c)
        s += out_p[(size_t)c * (BATCH * D_FEAT) + i];
    out[i] = s / lrow[i >> 6];
}

extern "C" void kernel_launch(void* const* d_in, const int* in_sizes, int n_in,
                              void* d_out, int out_size, void* d_ws, size_t ws_size,
                              hipStream_t stream) {
    const float* M = (const float*)d_in[0];   // memory [65536][64]
    const float* W = (const float*)d_in[1];   // weight [2048][65536]
    float* out = (float*)d_out;

    float*          lrow  = (float*)d_ws;                                  // 8 KB
    unsigned short* MT    = (unsigned short*)((char*)d_ws + (1 << 16));    // 8 MB
    float*          out_p = (float*)((char*)d_ws + (1 << 16) + (1 << 23)); // 16 MB

    hipMemsetAsync(d_ws, 0, (size_t)BATCH * sizeof(float), stream);

    convert_mt<<<N_SLOTS / 64, 256, 0, stream>>>(M, MT);
    reading_main<<<(BATCH / BM) * NC, 256, 0, stream>>>(MT, W, out_p, lrow);
    reading_finalize<<<(BATCH * D_FEAT) / 256, 256, 0, stream>>>(out_p, lrow, out);
}

// Round 7
// 117.580 us; speedup vs baseline: 1.7313x; 1.7313x over previous
//
#include <hip/hip_runtime.h>
#include <hip/hip_bf16.h>
#include <stdint.h>

typedef __attribute__((ext_vector_type(8))) short short8;
typedef __attribute__((ext_vector_type(4))) float f32x4;

#define N_SLOTS 65536
#define D_FEAT  64
#define BATCH   2048
#define BM      64               // batch rows per block
#define BK      128              // k per tile (512 B per W row)
#define NC      32               // k-chunk slots (by)
#define NITER   16               // tiles per block

// float -> bf16 bits, round-to-nearest-even
__device__ __forceinline__ unsigned short f2bf(float f) {
    unsigned int u = __builtin_bit_cast(unsigned int, f);
    u += 0x7fffu + ((u >> 16) & 1u);
    return (unsigned short)(u >> 16);
}
__device__ __forceinline__ unsigned int pk2(float a, float b) {
    return (unsigned int)f2bf(a) | ((unsigned int)f2bf(b) << 16);
}

// Kernel 0: M [N_SLOTS][64] f32 -> MT [64][N_SLOTS] bf16 (runs once, ~4 us)
__global__ __launch_bounds__(256) void convert_mt(const float* __restrict__ M,
                                                  unsigned short* __restrict__ MT) {
    __shared__ unsigned short s[64][72];
    const int t  = threadIdx.x;
    const int k0 = blockIdx.x * 64;
    #pragma unroll
    for (int j = 0; j < 4; ++j) {
        const int r = j * 16 + (t >> 4);
        const int c = (t & 15) * 4;
        const float4 v = *reinterpret_cast<const float4*>(M + (size_t)(k0 + r) * D_FEAT + c);
        s[r][c + 0] = f2bf(v.x); s[r][c + 1] = f2bf(v.y);
        s[r][c + 2] = f2bf(v.z); s[r][c + 3] = f2bf(v.w);
    }
    __syncthreads();
    #pragma unroll
    for (int j = 0; j < 2; ++j) {
        const int d  = j * 32 + (t >> 3);
        const int kk = (t & 7) * 8;
        short8 v;
        #pragma unroll
        for (int e = 0; e < 8; ++e) v[e] = (short)s[kk + e][d];
        *reinterpret_cast<short8*>(MT + (size_t)d * N_SLOTS + k0 + kk) = v;
    }
}

// Main: R5 structure (phased LDS, phase-rotated spread windows) + nt W loads
// + atomic epilogue (no partials buffer).
__global__ __launch_bounds__(256) void reading_main(
    const unsigned short* __restrict__ MT,  // [64][N_SLOTS] bf16
    const float* __restrict__ W,            // [BATCH][N_SLOTS] f32
    float* __restrict__ out,                // [BATCH][64] numerator accum (pre-zeroed)
    float* __restrict__ lrow)               // [BATCH] denominator accum (pre-zeroed)
{
    __shared__ __align__(16) unsigned short sA[BM * BK];      // 16 KB
    __shared__ __align__(16) unsigned short sB[D_FEAT * BK];  // 16 KB

    const int t  = threadIdx.x;
    const int ln = t & 63;
    const int wv = t >> 6;      // wave 0..3 -> batch rows 16*wv..16*wv+15
    const int r  = ln & 15;
    const int g  = ln >> 4;     // k lane-group 0..3
    const int hi = ln >> 5;     // 0/1 half-wave

    // bijective XCD swizzle: XCD (bid&7) keeps a fixed by-congruence class -> L2-local MT
    const int bid = blockIdx.x;
    const int wg  = ((bid & 7) << 7) | (bid >> 3);
    const int by  = wg >> 5;    // 0..31
    const int bx  = wg & 31;    // 0..31
    const int bm0 = bx * BM;

    // A staging: instr j loads rows wv*16 + j*2 + hi; 32 lanes x float4 = 512B/row
    const int    kq    = (ln & 31) * 4;
    const size_t wbase = (size_t)(bm0 + wv * 16 + hi) * N_SLOTS + kq;
    // B staging: instr i loads rows d = wv*16 + i*4 + (ln>>4); 16 lanes x short8
    const int    sd    = wv * 16 + (ln >> 4);
    const int    kb    = (ln & 15) * 8;
    const size_t mbase = (size_t)sd * N_SLOTS + kb;

    // column element-offset of tile s (phase-rotated interleaved tiling)
    #define COLOF(s) ((size_t)(((((s) + bx) & (NITER - 1)) * NC + by) * BK))

    float lsum[8];
    #pragma unroll
    for (int j = 0; j < 8; ++j) lsum[j] = 0.f;
    f32x4 acc[4];
    #pragma unroll
    for (int td = 0; td < 4; ++td) acc[td] = f32x4{0.f, 0.f, 0.f, 0.f};

    f32x4  pw[8];
    short8 pm[4];

    #define ISSUE(co) do { \
        _Pragma("unroll") for (int j = 0; j < 8; ++j) \
            pw[j] = __builtin_nontemporal_load( \
                reinterpret_cast<const f32x4*>(W + wbase + (size_t)j * 2 * N_SLOTS + (co))); \
        _Pragma("unroll") for (int i = 0; i < 4; ++i) \
            pm[i] = *reinterpret_cast<const short8*>(MT + mbase + (size_t)i * 4 * N_SLOTS + (co)); \
    } while (0)

    #define WRITE_STAGE() do { \
        _Pragma("unroll") for (int j = 0; j < 8; ++j) { \
            const float e0 = __expf(pw[j][0]), e1 = __expf(pw[j][1]); \
            const float e2 = __expf(pw[j][2]), e3 = __expf(pw[j][3]); \
            lsum[j] += (e0 + e1) + (e2 + e3); \
            const unsigned long long pk = (unsigned long long)pk2(e0, e1) \
                                        | ((unsigned long long)pk2(e2, e3) << 32); \
            const int rj = wv * 16 + j * 2 + hi; \
            *reinterpret_cast<unsigned long long*>(&sA[rj * BK + (kq ^ ((rj & 7) * 8))]) = pk; \
        } \
        _Pragma("unroll") for (int i = 0; i < 4; ++i) { \
            const int d = sd + i * 4; \
            *reinterpret_cast<short8*>(&sB[d * BK + (kb ^ ((d & 7) * 8))]) = pm[i]; \
        } \
    } while (0)

    #define COMPUTE() do { \
        _Pragma("unroll") for (int ks = 0; ks < 4; ++ks) { \
            const int ko = (ks * 32 + g * 8) ^ ((r & 7) * 8); \
            const short8 a = *reinterpret_cast<const short8*>(&sA[(16 * wv + r) * BK + ko]); \
            _Pragma("unroll") for (int td = 0; td < 4; ++td) { \
                const short8 b = *reinterpret_cast<const short8*>(&sB[(16 * td + r) * BK + ko]); \
                acc[td] = __builtin_amdgcn_mfma_f32_16x16x32_bf16(a, b, acc[td], 0, 0, 0); \
            } \
        } \
    } while (0)

    #define BAR_PLAIN() do { \
        __builtin_amdgcn_sched_barrier(0); \
        __builtin_amdgcn_s_barrier(); \
        __builtin_amdgcn_sched_barrier(0); \
    } while (0)

    #define BAR_LGKM() do { \
        __builtin_amdgcn_sched_barrier(0); \
        asm volatile("s_waitcnt lgkmcnt(0)" ::: "memory"); \
        __builtin_amdgcn_s_barrier(); \
        __builtin_amdgcn_sched_barrier(0); \
    } while (0)

    // prologue: stage tile 0
    ISSUE(COLOF(0));
    WRITE_STAGE();
    BAR_LGKM();

    #pragma unroll 1
    for (int s = 0; s < NITER; ++s) {
        const bool more = (s + 1 < NITER);
        if (more) { ISSUE(COLOF(s + 1)); __builtin_amdgcn_sched_barrier(0); }
        COMPUTE();          // ds_reads consumed by MFMA before barrier
        if (more) {
            BAR_PLAIN();    // all waves done reading sA/sB (W loads stay in flight)
            WRITE_STAGE();  // counted vmcnt waits here
            BAR_LGKM();     // staged writes visible to all waves
        }
    }

    // numerator tile -> atomics (C/D map col=r, row=g*4+q, verified R1)
    #pragma unroll
    for (int td = 0; td < 4; ++td) {
        #pragma unroll
        for (int q = 0; q < 4; ++q) {
            atomicAdd(&out[(size_t)(bm0 + 16 * wv + g * 4 + q) * D_FEAT + 16 * td + r],
                      acc[td][q]);
        }
    }

    // denominator: reduce within 32-lane halves (rows wv*16 + j*2 + hi)
    #pragma unroll
    for (int j = 0; j < 8; ++j) {
        float s2 = lsum[j];
        s2 += __shfl_xor(s2, 1, 64);
        s2 += __shfl_xor(s2, 2, 64);
        s2 += __shfl_xor(s2, 4, 64);
        s2 += __shfl_xor(s2, 8, 64);
        s2 += __shfl_xor(s2, 16, 64);
        if ((ln & 31) == 0)
            atomicAdd(&lrow[bm0 + wv * 16 + j * 2 + hi], s2);
    }
}

__global__ __launch_bounds__(256) void reading_finalize(
    float* __restrict__ out, const float* __restrict__ lrow)
{
    const int i = blockIdx.x * 256 + threadIdx.x;   // BATCH*D_FEAT total
    out[i] = out[i] / lrow[i >> 6];
}

extern "C" void kernel_launch(void* const* d_in, const int* in_sizes, int n_in,
                              void* d_out, int out_size, void* d_ws, size_t ws_size,
                              hipStream_t stream) {
    const float* M = (const float*)d_in[0];   // memory [65536][64]
    const float* W = (const float*)d_in[1];   // weight [2048][65536]
    float* out = (float*)d_out;

    float*          lrow = (float*)d_ws;                               // 8 KB
    unsigned short* MT   = (unsigned short*)((char*)d_ws + (1 << 16)); // 8 MB

    hipMemsetAsync(d_out, 0, (size_t)BATCH * D_FEAT * sizeof(float), stream);
    hipMemsetAsync(d_ws, 0, (size_t)BATCH * sizeof(float), stream);

    convert_mt<<<N_SLOTS / 64, 256, 0, stream>>>(M, MT);
    reading_main<<<(BATCH / BM) * NC, 256, 0, stream>>>(MT, W, out, lrow);
    reading_finalize<<<(BATCH * D_FEAT) / 256, 256, 0, stream>>>(out, lrow);
}

// Round 8
// 116.604 us; speedup vs baseline: 1.7458x; 1.0084x over previous
//
#include <hip/hip_runtime.h>
#include <hip/hip_bf16.h>
#include <stdint.h>

typedef __attribute__((ext_vector_type(8))) short short8;
typedef __attribute__((ext_vector_type(4))) float f32x4;

#define N_SLOTS 65536
#define D_FEAT  64
#define BATCH   2048
#define BM      64               // batch rows per block
#define BK      128              // k per tile (512 B per W row)
#define NC      32               // k-chunk slots (by)
#define NITER   16               // tiles per block (even!)

// float -> bf16 bits, round-to-nearest-even
__device__ __forceinline__ unsigned short f2bf(float f) {
    unsigned int u = __builtin_bit_cast(unsigned int, f);
    u += 0x7fffu + ((u >> 16) & 1u);
    return (unsigned short)(u >> 16);
}
__device__ __forceinline__ unsigned int pk2(float a, float b) {
    return (unsigned int)f2bf(a) | ((unsigned int)f2bf(b) << 16);
}

// Kernel 0: M [N_SLOTS][64] f32 -> MT [64][N_SLOTS] bf16 (runs once, ~4 us)
__global__ __launch_bounds__(256) void convert_mt(const float* __restrict__ M,
                                                  unsigned short* __restrict__ MT) {
    __shared__ unsigned short s[64][72];
    const int t  = threadIdx.x;
    const int k0 = blockIdx.x * 64;
    #pragma unroll
    for (int j = 0; j < 4; ++j) {
        const int r = j * 16 + (t >> 4);
        const int c = (t & 15) * 4;
        const float4 v = *reinterpret_cast<const float4*>(M + (size_t)(k0 + r) * D_FEAT + c);
        s[r][c + 0] = f2bf(v.x); s[r][c + 1] = f2bf(v.y);
        s[r][c + 2] = f2bf(v.z); s[r][c + 3] = f2bf(v.w);
    }
    __syncthreads();
    #pragma unroll
    for (int j = 0; j < 2; ++j) {
        const int d  = j * 32 + (t >> 3);
        const int kk = (t & 7) * 8;
        short8 v;
        #pragma unroll
        for (int e = 0; e < 8; ++e) v[e] = (short)s[kk + e][d];
        *reinterpret_cast<short8*>(MT + (size_t)d * N_SLOTS + k0 + kk) = v;
    }
}

// Main: R7 structure + depth-2 W register prefetch (pwA/pwB static alternation).
__global__ __launch_bounds__(256, 3) void reading_main(
    const unsigned short* __restrict__ MT,  // [64][N_SLOTS] bf16
    const float* __restrict__ W,            // [BATCH][N_SLOTS] f32
    float* __restrict__ out,                // [BATCH][64] numerator accum (pre-zeroed)
    float* __restrict__ lrow)               // [BATCH] denominator accum (pre-zeroed)
{
    __shared__ __align__(16) unsigned short sA[BM * BK];      // 16 KB
    __shared__ __align__(16) unsigned short sB[D_FEAT * BK];  // 16 KB

    const int t  = threadIdx.x;
    const int ln = t & 63;
    const int wv = t >> 6;      // wave 0..3 -> batch rows 16*wv..16*wv+15
    const int r  = ln & 15;
    const int g  = ln >> 4;     // k lane-group 0..3
    const int hi = ln >> 5;     // 0/1 half-wave

    // bijective XCD swizzle: XCD (bid&7) keeps a fixed by-congruence class -> L2-local MT
    const int bid = blockIdx.x;
    const int wg  = ((bid & 7) << 7) | (bid >> 3);
    const int by  = wg >> 5;    // 0..31
    const int bx  = wg & 31;    // 0..31
    const int bm0 = bx * BM;

    // A staging: instr j loads rows wv*16 + j*2 + hi; 32 lanes x float4 = 512B/row
    const int    kq    = (ln & 31) * 4;
    const size_t wbase = (size_t)(bm0 + wv * 16 + hi) * N_SLOTS + kq;
    // B staging: instr i loads rows d = wv*16 + i*4 + (ln>>4); 16 lanes x short8
    const int    sd    = wv * 16 + (ln >> 4);
    const int    kb    = (ln & 15) * 8;
    const size_t mbase = (size_t)sd * N_SLOTS + kb;

    // column element-offset of tile s (phase-rotated interleaved tiling)
    #define COLOF(s) ((size_t)(((((s) + bx) & (NITER - 1)) * NC + by) * BK))

    float lsum[8];
    #pragma unroll
    for (int j = 0; j < 8; ++j) lsum[j] = 0.f;
    f32x4 acc[4];
    #pragma unroll
    for (int td = 0; td < 4; ++td) acc[td] = f32x4{0.f, 0.f, 0.f, 0.f};

    f32x4  pwA[8], pwB[8];
    short8 pm[4];

    // W loads: nontemporal (stream-once; keep MT hot in L2)
    #define ISSUE_W(buf, co) do { \
        _Pragma("unroll") for (int j = 0; j < 8; ++j) \
            buf[j] = __builtin_nontemporal_load( \
                reinterpret_cast<const f32x4*>(W + wbase + (size_t)j * 2 * N_SLOTS + (co))); \
    } while (0)

    #define ISSUE_M(co) do { \
        _Pragma("unroll") for (int i = 0; i < 4; ++i) \
            pm[i] = *reinterpret_cast<const short8*>(MT + mbase + (size_t)i * 4 * N_SLOTS + (co)); \
    } while (0)

    #define WRITE_STAGE(buf) do { \
        _Pragma("unroll") for (int j = 0; j < 8; ++j) { \
            const float e0 = __expf(buf[j][0]), e1 = __expf(buf[j][1]); \
            const float e2 = __expf(buf[j][2]), e3 = __expf(buf[j][3]); \
            lsum[j] += (e0 + e1) + (e2 + e3); \
            const unsigned long long pk = (unsigned long long)pk2(e0, e1) \
                                        | ((unsigned long long)pk2(e2, e3) << 32); \
            const int rj = wv * 16 + j * 2 + hi; \
            *reinterpret_cast<unsigned long long*>(&sA[rj * BK + (kq ^ ((rj & 7) * 8))]) = pk; \
        } \
        _Pragma("unroll") for (int i = 0; i < 4; ++i) { \
            const int d = sd + i * 4; \
            *reinterpret_cast<short8*>(&sB[d * BK + (kb ^ ((d & 7) * 8))]) = pm[i]; \
        } \
    } while (0)

    #define COMPUTE() do { \
        _Pragma("unroll") for (int ks = 0; ks < 4; ++ks) { \
            const int ko = (ks * 32 + g * 8) ^ ((r & 7) * 8); \
            const short8 a = *reinterpret_cast<const short8*>(&sA[(16 * wv + r) * BK + ko]); \
            _Pragma("unroll") for (int td = 0; td < 4; ++td) { \
                const short8 b = *reinterpret_cast<const short8*>(&sB[(16 * td + r) * BK + ko]); \
                acc[td] = __builtin_amdgcn_mfma_f32_16x16x32_bf16(a, b, acc[td], 0, 0, 0); \
            } \
        } \
    } while (0)

    #define BAR_PLAIN() do { \
        __builtin_amdgcn_sched_barrier(0); \
        __builtin_amdgcn_s_barrier(); \
        __builtin_amdgcn_sched_barrier(0); \
    } while (0)

    #define BAR_LGKM() do { \
        __builtin_amdgcn_sched_barrier(0); \
        asm volatile("s_waitcnt lgkmcnt(0)" ::: "memory"); \
        __builtin_amdgcn_s_barrier(); \
        __builtin_amdgcn_sched_barrier(0); \
    } while (0)

    // ---- prologue: pm+pwA for tile 0, prefetch pwB <- tile 1, stage tile 0
    ISSUE_M(COLOF(0));
    ISSUE_W(pwA, COLOF(0));
    ISSUE_W(pwB, COLOF(1));          // depth-2: stays in flight across stage 0
    WRITE_STAGE(pwA);                // waits pm+pwA (vmcnt(8)); pwB survives
    BAR_LGKM();

    #pragma unroll 1
    for (int s = 0; s < NITER; s += 2) {
        // even half: compute s; stage s+1 (pwB); prefetch M(s+1) then W(s+2)->pwA
        ISSUE_M(COLOF(s + 1));                          // s+1 <= 15 always
        if (s + 2 < NITER) ISSUE_W(pwA, COLOF(s + 2));
        __builtin_amdgcn_sched_barrier(0);
        COMPUTE();
        BAR_PLAIN();                 // sA/sB reads done; W prefetch stays in flight
        WRITE_STAGE(pwB);            // waits pm (vmcnt(8)); pwA prefetch survives
        BAR_LGKM();

        // odd half: compute s+1; stage s+2 (pwA); prefetch M(s+2), W(s+3)->pwB
        if (s + 2 < NITER) {
            ISSUE_M(COLOF(s + 2));
            if (s + 3 < NITER) ISSUE_W(pwB, COLOF(s + 3));
            __builtin_amdgcn_sched_barrier(0);
        }
        COMPUTE();
        if (s + 2 < NITER) {
            BAR_PLAIN();
            WRITE_STAGE(pwA);        // waits pm (vmcnt(8)); pwB prefetch survives
            BAR_LGKM();
        }
    }

    // numerator tile -> atomics (C/D map col=r, row=g*4+q, verified R1)
    #pragma unroll
    for (int td = 0; td < 4; ++td) {
        #pragma unroll
        for (int q = 0; q < 4; ++q) {
            atomicAdd(&out[(size_t)(bm0 + 16 * wv + g * 4 + q) * D_FEAT + 16 * td + r],
                      acc[td][q]);
        }
    }

    // denominator: reduce within 32-lane halves (rows wv*16 + j*2 + hi)
    #pragma unroll
    for (int j = 0; j < 8; ++j) {
        float s2 = lsum[j];
        s2 += __shfl_xor(s2, 1, 64);
        s2 += __shfl_xor(s2, 2, 64);
        s2 += __shfl_xor(s2, 4, 64);
        s2 += __shfl_xor(s2, 8, 64);
        s2 += __shfl_xor(s2, 16, 64);
        if ((ln & 31) == 0)
            atomicAdd(&lrow[bm0 + wv * 16 + j * 2 + hi], s2);
    }
}

__global__ __launch_bounds__(256) void reading_finalize(
    float* __restrict__ out, const float* __restrict__ lrow)
{
    const int i = blockIdx.x * 256 + threadIdx.x;   // BATCH*D_FEAT total
    out[i] = out[i] / lrow[i >> 6];
}

extern "C" void kernel_launch(void* const* d_in, const int* in_sizes, int n_in,
                              void* d_out, int out_size, void* d_ws, size_t ws_size,
                              hipStream_t stream) {
    const float* M = (const float*)d_in[0];   // memory [65536][64]
    const float* W = (const float*)d_in[1];   // weight [2048][65536]
    float* out = (float*)d_out;

    float*          lrow = (float*)d_ws;                               // 8 KB
    unsigned short* MT   = (unsigned short*)((char*)d_ws + (1 << 16)); // 8 MB

    hipMemsetAsync(d_out, 0, (size_t)BATCH * D_FEAT * sizeof(float), stream);
    hipMemsetAsync(d_ws, 0, (size_t)BATCH * sizeof(float), stream);

    convert_mt<<<N_SLOTS / 64, 256, 0, stream>>>(M, MT);
    reading_main<<<(BATCH / BM) * NC, 256, 0, stream>>>(MT, W, out, lrow);
    reading_finalize<<<(BATCH * D_FEAT) / 256, 256, 0, stream>>>(out, lrow);
}

// Round 9
// 110.791 us; speedup vs baseline: 1.8374x; 1.0525x over previous
//
#include <hip/hip_runtime.h>
#include <hip/hip_bf16.h>
#include <stdint.h>

typedef __attribute__((ext_vector_type(8))) short short8;
typedef __attribute__((ext_vector_type(4))) float f32x4;

#define N_SLOTS 65536
#define D_FEAT  64
#define BATCH   2048
#define BM      64               // batch rows per block
#define BK      128              // k per tile (512 B per W row)
#define NC      32               // k-chunk slots (by)
#define NITER   16               // tiles per block

// float -> bf16 bits, round-to-nearest-even
__device__ __forceinline__ unsigned short f2bf(float f) {
    unsigned int u = __builtin_bit_cast(unsigned int, f);
    u += 0x7fffu + ((u >> 16) & 1u);
    return (unsigned short)(u >> 16);
}
__device__ __forceinline__ unsigned int pk2(float a, float b) {
    return (unsigned int)f2bf(a) | ((unsigned int)f2bf(b) << 16);
}

// Kernel 0: M -> MT (bf16 transposed) AND zero out/lrow (folds the 2 memsets)
__global__ __launch_bounds__(256) void convert_mt(const float* __restrict__ M,
                                                  unsigned short* __restrict__ MT,
                                                  float* __restrict__ out,
                                                  float* __restrict__ lrow) {
    __shared__ unsigned short s[64][72];
    const int t  = threadIdx.x;
    const int k0 = blockIdx.x * 64;

    // fused zeroing: 1024 blocks cover out (131072 f32) and lrow (2048 f32)
    if (t < 128) out[blockIdx.x * 128 + t] = 0.f;
    else if (t < 130) lrow[blockIdx.x * 2 + (t - 128)] = 0.f;

    #pragma unroll
    for (int j = 0; j < 4; ++j) {
        const int r = j * 16 + (t >> 4);
        const int c = (t & 15) * 4;
        const float4 v = *reinterpret_cast<const float4*>(M + (size_t)(k0 + r) * D_FEAT + c);
        s[r][c + 0] = f2bf(v.x); s[r][c + 1] = f2bf(v.y);
        s[r][c + 2] = f2bf(v.z); s[r][c + 3] = f2bf(v.w);
    }
    __syncthreads();
    #pragma unroll
    for (int j = 0; j < 2; ++j) {
        const int d  = j * 32 + (t >> 3);
        const int kk = (t & 7) * 8;
        short8 v;
        #pragma unroll
        for (int e = 0; e < 8; ++e) v[e] = (short)s[kk + e][d];
        *reinterpret_cast<short8*>(MT + (size_t)d * N_SLOTS + k0 + kk) = v;
    }
}

// Main: R7 structure (phased LDS, phase-rotated spread windows, nt W loads,
// atomic epilogue). Measured ~105 us; at this pattern's DRAM ceiling.
__global__ __launch_bounds__(256) void reading_main(
    const unsigned short* __restrict__ MT,  // [64][N_SLOTS] bf16
    const float* __restrict__ W,            // [BATCH][N_SLOTS] f32
    float* __restrict__ out,                // [BATCH][64] numerator accum (pre-zeroed)
    float* __restrict__ lrow)               // [BATCH] denominator accum (pre-zeroed)
{
    __shared__ __align__(16) unsigned short sA[BM * BK];      // 16 KB
    __shared__ __align__(16) unsigned short sB[D_FEAT * BK];  // 16 KB

    const int t  = threadIdx.x;
    const int ln = t & 63;
    const int wv = t >> 6;      // wave 0..3 -> batch rows 16*wv..16*wv+15
    const int r  = ln & 15;
    const int g  = ln >> 4;     // k lane-group 0..3
    const int hi = ln >> 5;     // 0/1 half-wave

    // bijective XCD swizzle: XCD (bid&7) keeps a fixed by-congruence class -> L2-local MT
    const int bid = blockIdx.x;
    const int wg  = ((bid & 7) << 7) | (bid >> 3);
    const int by  = wg >> 5;    // 0..31
    const int bx  = wg & 31;    // 0..31
    const int bm0 = bx * BM;

    // A staging: instr j loads rows wv*16 + j*2 + hi; 32 lanes x float4 = 512B/row
    const int    kq    = (ln & 31) * 4;
    const size_t wbase = (size_t)(bm0 + wv * 16 + hi) * N_SLOTS + kq;
    // B staging: instr i loads rows d = wv*16 + i*4 + (ln>>4); 16 lanes x short8
    const int    sd    = wv * 16 + (ln >> 4);
    const int    kb    = (ln & 15) * 8;
    const size_t mbase = (size_t)sd * N_SLOTS + kb;

    // column element-offset of tile s (phase-rotated interleaved tiling)
    #define COLOF(s) ((size_t)(((((s) + bx) & (NITER - 1)) * NC + by) * BK))

    float lsum[8];
    #pragma unroll
    for (int j = 0; j < 8; ++j) lsum[j] = 0.f;
    f32x4 acc[4];
    #pragma unroll
    for (int td = 0; td < 4; ++td) acc[td] = f32x4{0.f, 0.f, 0.f, 0.f};

    f32x4  pw[8];
    short8 pm[4];

    #define ISSUE(co) do { \
        _Pragma("unroll") for (int j = 0; j < 8; ++j) \
            pw[j] = __builtin_nontemporal_load( \
                reinterpret_cast<const f32x4*>(W + wbase + (size_t)j * 2 * N_SLOTS + (co))); \
        _Pragma("unroll") for (int i = 0; i < 4; ++i) \
            pm[i] = *reinterpret_cast<const short8*>(MT + mbase + (size_t)i * 4 * N_SLOTS + (co)); \
    } while (0)

    #define WRITE_STAGE() do { \
        _Pragma("unroll") for (int j = 0; j < 8; ++j) { \
            const float e0 = __expf(pw[j][0]), e1 = __expf(pw[j][1]); \
            const float e2 = __expf(pw[j][2]), e3 = __expf(pw[j][3]); \
            lsum[j] += (e0 + e1) + (e2 + e3); \
            const unsigned long long pk = (unsigned long long)pk2(e0, e1) \
                                        | ((unsigned long long)pk2(e2, e3) << 32); \
            const int rj = wv * 16 + j * 2 + hi; \
            *reinterpret_cast<unsigned long long*>(&sA[rj * BK + (kq ^ ((rj & 7) * 8))]) = pk; \
        } \
        _Pragma("unroll") for (int i = 0; i < 4; ++i) { \
            const int d = sd + i * 4; \
            *reinterpret_cast<short8*>(&sB[d * BK + (kb ^ ((d & 7) * 8))]) = pm[i]; \
        } \
    } while (0)

    #define COMPUTE() do { \
        _Pragma("unroll") for (int ks = 0; ks < 4; ++ks) { \
            const int ko = (ks * 32 + g * 8) ^ ((r & 7) * 8); \
            const short8 a = *reinterpret_cast<const short8*>(&sA[(16 * wv + r) * BK + ko]); \
            _Pragma("unroll") for (int td = 0; td < 4; ++td) { \
                const short8 b = *reinterpret_cast<const short8*>(&sB[(16 * td + r) * BK + ko]); \
                acc[td] = __builtin_amdgcn_mfma_f32_16x16x32_bf16(a, b, acc[td], 0, 0, 0); \
            } \
        } \
    } while (0)

    #define BAR_PLAIN() do { \
        __builtin_amdgcn_sched_barrier(0); \
        __builtin_amdgcn_s_barrier(); \
        __builtin_amdgcn_sched_barrier(0); \
    } while (0)

    #define BAR_LGKM() do { \
        __builtin_amdgcn_sched_barrier(0); \
        asm volatile("s_waitcnt lgkmcnt(0)" ::: "memory"); \
        __builtin_amdgcn_s_barrier(); \
        __builtin_amdgcn_sched_barrier(0); \
    } while (0)

    // prologue: stage tile 0
    ISSUE(COLOF(0));
    WRITE_STAGE();
    BAR_LGKM();

    #pragma unroll 1
    for (int s = 0; s < NITER; ++s) {
        const bool more = (s + 1 < NITER);
        if (more) { ISSUE(COLOF(s + 1)); __builtin_amdgcn_sched_barrier(0); }
        COMPUTE();          // ds_reads consumed by MFMA before barrier
        if (more) {
            BAR_PLAIN();    // all waves done reading sA/sB (W loads stay in flight)
            WRITE_STAGE();  // counted vmcnt waits here
            BAR_LGKM();     // staged writes visible to all waves
        }
    }

    // numerator tile -> atomics (C/D map col=r, row=g*4+q, verified R1)
    #pragma unroll
    for (int td = 0; td < 4; ++td) {
        #pragma unroll
        for (int q = 0; q < 4; ++q) {
            atomicAdd(&out[(size_t)(bm0 + 16 * wv + g * 4 + q) * D_FEAT + 16 * td + r],
                      acc[td][q]);
        }
    }

    // denominator: reduce within 32-lane halves (rows wv*16 + j*2 + hi)
    #pragma unroll
    for (int j = 0; j < 8; ++j) {
        float s2 = lsum[j];
        s2 += __shfl_xor(s2, 1, 64);
        s2 += __shfl_xor(s2, 2, 64);
        s2 += __shfl_xor(s2, 4, 64);
        s2 += __shfl_xor(s2, 8, 64);
        s2 += __shfl_xor(s2, 16, 64);
        if ((ln & 31) == 0)
            atomicAdd(&lrow[bm0 + wv * 16 + j * 2 + hi], s2);
    }
}

__global__ __launch_bounds__(256) void reading_finalize(
    float* __restrict__ out, const float* __restrict__ lrow)
{
    const int i = blockIdx.x * 256 + threadIdx.x;   // BATCH*D_FEAT total
    out[i] = out[i] / lrow[i >> 6];
}

extern "C" void kernel_launch(void* const* d_in, const int* in_sizes, int n_in,
                              void* d_out, int out_size, void* d_ws, size_t ws_size,
                              hipStream_t stream) {
    const float* M = (const float*)d_in[0];   // memory [65536][64]
    const float* W = (const float*)d_in[1];   // weight [2048][65536]
    float* out = (float*)d_out;

    float*          lrow = (float*)d_ws;                               // 8 KB
    unsigned short* MT   = (unsigned short*)((char*)d_ws + (1 << 16)); // 8 MB

    convert_mt<<<N_SLOTS / 64, 256, 0, stream>>>(M, MT, out, lrow);
    reading_main<<<(BATCH / BM) * NC, 256, 0, stream>>>(MT, W, out, lrow);
    reading_finalize<<<(BATCH * D_FEAT) / 256, 256, 0, stream>>>(out, lrow);
}